// Round 7
// baseline (207.388 us; speedup 1.0000x reference)
//
#include <hip/hip_runtime.h>
#include <float.h>

typedef int i32x16 __attribute__((ext_vector_type(16)));

#define NTOK  65536
#define DIM   256
#define NCODE 1024
#define TT    64          // tokens per block; grid = 1024 -> 4 blocks/CU (LDS ~22 KB, VGPR ~80)
#define NCT   16          // 16 code-tiles of 64 codes
#define CAP   4096
#define TAU   0.35f       // covers 6.4 sigma of i8-quantization distance noise
#define BIAS  64.0f       // coarse scores strictly positive -> uint order == float order
#define SX    20.0f       // x quant scale: clamp at 6.35 sigma (P(clip) ~ 4e-3 over all elems)
#define SW    360.0f      // w quant scale: w sigma = 1/16, clamp at 5.6 sigma

__device__ inline unsigned q4(float4 v, float s) {
    int q0 = (int)rintf(fminf(fmaxf(v.x * s, -127.f), 127.f));
    int q1 = (int)rintf(fminf(fmaxf(v.y * s, -127.f), 127.f));
    int q2 = (int)rintf(fminf(fmaxf(v.z * s, -127.f), 127.f));
    int q3 = (int)rintf(fminf(fmaxf(v.w * s, -127.f), 127.f));
    return (unsigned)(q0 & 255) | ((unsigned)(q1 & 255) << 8) |
           ((unsigned)(q2 & 255) << 16) | ((unsigned)(q3 & 255) << 24);
}
__device__ inline long pk8(float4 a, float4 b, float s) {
    union { unsigned u[2]; long l; } r;
    r.u[0] = q4(a, s); r.u[1] = q4(b, s);
    return r.l;
}
__device__ inline unsigned umn(unsigned a, unsigned b) { return a < b ? a : b; }
__device__ inline unsigned umx(unsigned a, unsigned b) { return a > b ? a : b; }

// async 16B global->LDS; LDS dest is wave-uniform base + lane*16 by construction
__device__ inline void gload16(const void* g, void* l) {
    __builtin_amdgcn_global_load_lds(
        (__attribute__((address_space(1))) void*)(size_t)g,
        (__attribute__((address_space(3))) void*)l,
        16, 0, 0);
}

// pre-kernel: ||W_k||^2 (fp64->fp32, from EXACT fp32 W) + W -> i8 in K-MAJOR tile
// layout: tile ct (64 codes), 8B-granule g (0..31), row r (0..63) at
// wq[ct*2048 + g*64 + r]. This makes the vq staging PURE LINEAR gload16 and the
// ds_read_b64 pattern bank-conflict-free (banks 2*ln mod 32: 4 touches/bank = min).
__global__ __launch_bounds__(256) void prep_kernel(const float* __restrict__ W,
                                                   float* __restrict__ nw_out,
                                                   long* __restrict__ wq_out) {
    const int tid = threadIdx.x;
    const int k = blockIdx.x * 8 + (tid >> 5);
    const int c = tid & 31;          // granule index
    const float4* wr = (const float4*)(W + (size_t)k * DIM + c * 8);
    float4 u = wr[0], v = wr[1];
    wq_out[(size_t)(k >> 6) * 2048 + (size_t)c * 64 + (k & 63)] = pk8(u, v, SW);
    double a = (double)u.x * u.x + (double)u.y * u.y + (double)u.z * u.z + (double)u.w * u.w
             + (double)v.x * v.x + (double)v.y * v.y + (double)v.z * v.z + (double)v.w * v.w;
    #pragma unroll
    for (int m = 1; m <= 16; m <<= 1) a += __shfl_xor(a, m);   // within 32-lane group
    if (c == 0) nw_out[k] = (float)a;
}

// (256,2): known-safe allocator config (R6: 76 arch VGPRs, zero spill). With true
// pressure ~80 < 128, 4 blocks/CU fit (grid 1024 -> 4/CU, LDS 22KB -> 7/CU cap).
// (4,4)/waves_per_eu squeeze to 64 regs + spill (R1/R3) -- do not use.
template <bool PRE>
__global__ __launch_bounds__(256, 2)
void vq_kernel(
    const float* __restrict__ x, const float* __restrict__ W,
    const float* __restrict__ nwp, const long* __restrict__ wqp,
    float* __restrict__ outq, float* __restrict__ outidx)
{
    __shared__ __align__(16) char wtile[16384];     // i8 tile (K-major); aliased as cand list
    __shared__ float nw_s[NCODE];                   // 4 KB
    __shared__ float nx_s[TT];
    __shared__ unsigned tmin_s[TT];                 // per-token global coarse min (packed)
    __shared__ unsigned long long best64[TT];
    __shared__ int cnt_s;
    __shared__ int bk_s[TT];
    unsigned* cand = (unsigned*)wtile;

    const int tid = threadIdx.x, tb = blockIdx.x * TT;
    const int wv = tid >> 6, l = tid & 63;
    const int ln = l & 31;          // A: token row / B: code col within 32
    const int h = l >> 5;           // K-half selector (which 8B granule of a K=16 step)
    const int tg = wv & 1;          // token half (32 tokens)
    const int cg = wv >> 1;         // code half of each 64-code tile (32 codes)

    // ---- nw: load precomputed, or fp64 in-block fallback ----
    if (PRE) {
        ((float4*)nw_s)[tid] = ((const float4*)nwp)[tid];
    } else {
        #pragma unroll
        for (int c = 0; c < 4; ++c) {
            const int k = (tid << 2) + c;
            const float4* wr = (const float4*)(W + (size_t)k * DIM);
            double a0 = 0.0, a1 = 0.0;
            for (int q = 0; q < DIM / 4; ++q) {
                float4 v = wr[q];
                a0 += (double)v.x * v.x + (double)v.y * v.y;
                a1 += (double)v.z * v.z + (double)v.w * v.w;
            }
            nw_s[k] = (float)(a0 + a1);
        }
    }
    if (tid == 0) cnt_s = 0;
    if (tid < TT) { best64[tid] = ~0ull; tmin_s[tid] = 0xFFFFFFFFu; }

    // ---- A-fragments: wave owns 32 tokens (i8, 16 K-granules = 32 VGPR) ----
    // lane (ln,h): token tg*32+ln, dims sp*16 + h*8 + [0..7]; cg=0 waves also do
    // the fused fp64 token norm (h=0/h=1 cover disjoint dim halves).
    const int trow = tb + (tg << 5) + ln;
    long xa[16];
    {
        const float4* xr = (const float4*)(x + (size_t)trow * DIM);
        double a0 = 0.0, a1 = 0.0;
        #pragma unroll
        for (int sp = 0; sp < 16; ++sp) {
            float4 u = xr[(sp << 2) + (h << 1)];
            float4 v = xr[(sp << 2) + (h << 1) + 1];
            xa[sp] = pk8(u, v, SX);
            if (cg == 0) {   // wave-uniform predicate
                a0 += (double)u.x * u.x + (double)u.y * u.y + (double)v.x * v.x + (double)v.y * v.y;
                a1 += (double)u.z * u.z + (double)u.w * u.w + (double)v.z * v.z + (double)v.w * v.w;
            }
        }
        if (cg == 0) {
            double nx = a0 + a1;
            nx += __shfl_xor(nx, 32);               // combine the two dim-halves
            if (h == 0) nx_s[(tg << 5) + ln] = (float)nx;
        }
    }

    // per-lane top-2 packed keys per C-reg row slot (16 token rows per lane)
    unsigned b0[16], b1[16];
    #pragma unroll
    for (int j = 0; j < 16; ++j) { b0[j] = 0xFFFFFFFFu; b1[j] = 0xFFFFFFFFu; }

    const float M2 = -2.0f / (SX * SW);             // i32 dot -> -2*sim (exact fp32 conv)

    for (int ct = 0; ct < NCT; ++ct) {
        __syncthreads();   // prior MFMA readers of wtile done
        if (PRE) {
            // PURE LINEAR async staging of the K-major tile (no swizzle needed)
            #pragma unroll
            for (int j = 0; j < 4; ++j) {
                const int C = j * 256 + tid;
                gload16((const char*)wqp + (size_t)ct * 16384 + (size_t)C * 16,
                        wtile + (size_t)C * 16);
            }
        } else {
            // in-kernel quantize fallback straight into K-major layout
            const int n = tid >> 2, q = tid & 3;
            const float4* srcp = (const float4*)(W + (size_t)(ct * 64 + n) * DIM + (q << 6));
            #pragma unroll
            for (int i = 0; i < 8; ++i) {
                float4 f0 = srcp[2 * i], f1 = srcp[2 * i + 1];
                const int g = (q << 3) + i;
                *(long*)(wtile + ((size_t)(g << 6) + n) * 8) = pk8(f0, f1, SW);
            }
        }
        __syncthreads();   // drains vmcnt (global_load_lds) / lgkmcnt

        // 32 tokens x 32 codes per wave: 16 conflict-free ds_read_b64 + 16 MFMA.
        // byte = (2sp+h)*512 + cg*256 + ln*8 -> base reg + compile-time sp<<10 offset.
        i32x16 acc;
        #pragma unroll
        for (int j = 0; j < 16; ++j) acc[j] = 0;

        const char* bp = wtile + (h << 9) + (cg << 8) + (ln << 3);
        #pragma unroll
        for (int sp = 0; sp < 16; ++sp) {
            long bq = *(const long*)(bp + (sp << 10));
            acc = __builtin_amdgcn_mfma_i32_32x32x16_i8(xa[sp], bq, acc, 0, 0, 0);
        }

        // ---- branch-free register top-2 on packed (score,k) keys ----
        const int kk = (ct << 6) + (cg << 5) + ln;
        const float nwb = nw_s[kk] + BIAS;
        #pragma unroll
        for (int j = 0; j < 16; ++j) {
            const float cs = fmaf((float)acc[j], M2, nwb);
            const unsigned u = (__float_as_uint(cs) & 0xFFFFFC00u) | (unsigned)kk;
            const unsigned lo = umn(u, b0[j]), hi = umx(u, b0[j]);
            b0[j] = lo; b1[j] = umn(hi, b1[j]);
        }
    }

    // ---- per-token coarse min: 32-lane reduce, then cross-wave atomicMin combine
    // (each token's 1024 codes are split across the two cg waves) ----
    #pragma unroll
    for (int j = 0; j < 16; ++j) {
        unsigned v = b0[j];
        #pragma unroll
        for (int m = 1; m <= 16; m <<= 1) v = umn(v, (unsigned)__shfl_xor((int)v, m));
        if (ln == 0) {
            const int t = (tg << 5) + (j & 3) + ((j >> 2) << 3) + (h << 2);  // C/D row map
            atomicMin(&tmin_s[t], v & 0xFFFFFC00u);
        }
    }
    __syncthreads();   // tmin ready; all MFMA reads of wtile done -> alias as cand list

    // ---- tau-trigger append against the global threshold ----
    #pragma unroll
    for (int j = 0; j < 16; ++j) {
        const int t = (tg << 5) + (j & 3) + ((j >> 2) << 3) + (h << 2);
        const float thr = __uint_as_float(tmin_s[t]) + TAU;
        if (__uint_as_float(b0[j] & 0xFFFFFC00u) <= thr) {
            int i = atomicAdd(&cnt_s, 1);
            if (i < CAP) cand[i] = ((unsigned)t << 10) | (b0[j] & 1023u);
        }
        if (__uint_as_float(b1[j] & 0xFFFFFC00u) <= thr) {
            int i = atomicAdd(&cnt_s, 1);
            if (i < CAP) cand[i] = ((unsigned)t << 10) | (b1[j] & 1023u);
        }
    }
    __syncthreads();

    // ---- wave-cooperative exact fp32 rescore; lexicographic (dv,k) atomicMin ----
    const int nc = min(cnt_s, CAP);
    for (int c = wv; c < nc; c += 4) {
        const unsigned en = cand[c];
        const int t = en >> 10, k = en & 1023;
        float4 xv = ((const float4*)(x + (size_t)(tb + t) * DIM))[l];
        float4 wr = ((const float4*)(W + (size_t)k * DIM))[l];
        float s = fmaf(xv.x, wr.x, fmaf(xv.y, wr.y, fmaf(xv.z, wr.z, xv.w * wr.w)));
        #pragma unroll
        for (int m = 1; m <= 32; m <<= 1) s += __shfl_xor(s, m);
        const float dv = (nx_s[t] + nw_s[k]) - 2.0f * s;
        if (l == 0) {
            unsigned long long key = ((unsigned long long)__float_as_uint(dv) << 32) | (unsigned)k;
            atomicMin(&best64[t], key);
        }
    }
    __syncthreads();

    if (tid < TT) {
        const int bk = (int)(best64[tid] & 1023u);
        bk_s[tid] = bk;
        outidx[tb + tid] = (float)bk;   // whole d_out read back as fp32
    }
    __syncthreads();

    // ---- gather codebook rows -> quantized output (coalesced float4) ----
    for (int i = tid; i < TT * (DIM / 4); i += 256) {
        const int t = i >> 6, j = i & 63;
        const float4* wr = (const float4*)(W + (size_t)bk_s[t] * DIM);
        ((float4*)(outq + (size_t)(tb + t) * DIM))[j] = wr[j];
    }
}

extern "C" void kernel_launch(void* const* d_in, const int* in_sizes, int n_in,
                              void* d_out, int out_size, void* d_ws, size_t ws_size,
                              hipStream_t stream) {
    const float* x = (const float*)d_in[0];
    const float* W = (const float*)d_in[1];
    float* outq   = (float*)d_out;
    float* outidx = outq + (size_t)NTOK * DIM;

    const size_t need = 4096 + (size_t)NCODE * DIM;   // nw (4KB) + i8 codebook (256KB)
    if (ws_size >= need) {
        float* nw_ws = (float*)d_ws;
        long* wq_ws = (long*)((char*)d_ws + 4096);
        prep_kernel<<<NCODE / 8, 256, 0, stream>>>(W, nw_ws, wq_ws);
        vq_kernel<true><<<NTOK / TT, 256, 0, stream>>>(x, W, nw_ws, wq_ws, outq, outidx);
    } else {
        vq_kernel<false><<<NTOK / TT, 256, 0, stream>>>(x, W, nullptr, nullptr, outq, outidx);
    }
}